// Round 4
// baseline (207.294 us; speedup 1.0000x reference)
//
#include <hip/hip_runtime.h>
#include <hip/hip_bf16.h>
#include <cstdint>

#define VDIM 10000
#define VPAD 10016          // 313 * 32, zero-padded K for MFMA
#define NROW 4096
#define DDIM 128
#define KSTEPS 313          // ceil(10000/32)
#define KSPLIT 8
#define KCHUNK 40           // ceil(313/8)

typedef __attribute__((ext_vector_type(8))) short bf16x8;
typedef __attribute__((ext_vector_type(4))) float f32x4;

__device__ __forceinline__ unsigned short f2bf(float f) {
    union { float f; unsigned u; } v; v.f = f;
    unsigned u = v.u;
    unsigned r = (u + 0x7FFFu + ((u >> 16) & 1u)) >> 16;  // RNE
    return (unsigned short)r;
}

// ---------------------------------------------------------------------------
// Kernel 1: convert embeddings fp32 [128][10000] -> bf16 [2][128][10016], pad=0
// ---------------------------------------------------------------------------
__global__ __launch_bounds__(256) void convert_emb(
    const float* __restrict__ ec, const float* __restrict__ er,
    unsigned short* __restrict__ out)
{
    int idx8 = (blockIdx.x * 256 + threadIdx.x) * 8;
    const int total = 2 * DDIM * VPAD;
    if (idx8 >= total) return;
    int e   = idx8 / (DDIM * VPAD);
    int rem = idx8 - e * (DDIM * VPAD);
    int row = rem / VPAD;
    int k   = rem - row * VPAD;
    unsigned short o[8];
    if (k < VDIM) {
        const float* src = (e ? er : ec) + row * VDIM + k;
        #pragma unroll
        for (int j = 0; j < 8; ++j) o[j] = f2bf(src[j]);
    } else {
        #pragma unroll
        for (int j = 0; j < 8; ++j) o[j] = 0;
    }
    *reinterpret_cast<bf16x8*>(out + idx8) = *reinterpret_cast<const bf16x8*>(o);
}

// ---------------------------------------------------------------------------
// Kernel 2: three GEMMs [4096,10000]x[10000,128] -> reps[3][4096][128] (f32)
// grid = (32 rb x 3 stream x 8 kc), block 256 (4 waves), wave owns 32 rows.
// Pipeline per kt (ONE raw s_barrier, no vmcnt drain):
//   convert A(t) [loaded 1 kt ago] -> issue A(t+1) -> ds_write B(t+1)
//   [loaded 3 kt ago] -> issue B(t+3) -> ds_read buf(t) -> MFMA -> s_barrier
// Cross-wave safety: each wave's pre-barrier ds_read waits (in-order DS queue)
// drain its own older ds_write; raw barrier then publishes to other waves.
// ---------------------------------------------------------------------------
__global__ __launch_bounds__(256, 3) void gemm_rep(
    const float* __restrict__ a0, const float* __restrict__ a1,
    const float* __restrict__ a2,
    const unsigned short* __restrict__ emb,   // [2][128][VPAD] bf16
    float* __restrict__ reps)                 // [3][4096][128] f32 (zeroed)
{
    __shared__ short bLds[2][DDIM][40];       // 20,480 B, padded rows (80 B)

    const int rb = blockIdx.x;
    const int s  = blockIdx.y;
    const int kc = blockIdx.z;
    const float* A = (s == 0) ? a0 : (s == 1 ? a1 : a2);
    const unsigned short* E = emb + (size_t)(s == 0 ? 0 : 1) * (DDIM * VPAD);

    const int tid  = threadIdx.x;
    const int wave = tid >> 6;
    const int lane = tid & 63;
    const int l15  = lane & 15;
    const int quad = lane >> 4;

    // B staging: thread t owns col=t>>1, half=t&1 (16 shorts = 32 B)
    const int scol  = tid >> 1;
    const int shalf = tid & 1;
    const unsigned short* sp = E + (size_t)scol * VPAD + shalf * 16;

    const int kt0 = kc * KCHUNK;
    const int kt1 = (kt0 + KCHUNK < KSTEPS) ? (kt0 + KCHUNK) : KSTEPS;

    const int r0 = rb * 128 + wave * 32;
    const float* ap0 = A + (size_t)(r0 + l15) * VDIM;
    const float* ap1 = A + (size_t)(r0 + 16 + l15) * VDIM;

    f32x4 acc[2][8];
    #pragma unroll
    for (int rf = 0; rf < 2; ++rf)
        #pragma unroll
        for (int ct = 0; ct < 8; ++ct) acc[rf][ct] = (f32x4){0.f, 0.f, 0.f, 0.f};

    bf16x8 sA0, sA1, sB0, sB1;          // two B stage pairs (named, ping-pong)
    f32x4 ar0, ar1, ar2, ar3;           // raw A for one kt (two row-frags)
    bf16x8 af0, af1;                    // converted A fragments

#define CLAMPK(KT) (((KT) < KSTEPS - 1) ? (KT) : (KSTEPS - 1))

#define GLOADB(sa, sb, KT) do {                                        \
        const unsigned short* q_ = sp + (size_t)(KT) * 32;             \
        sa = *reinterpret_cast<const bf16x8*>(q_);                     \
        sb = *reinterpret_cast<const bf16x8*>(q_ + 8);                 \
    } while (0)

#define GLOADA(KT) do {                                                \
        int koA_ = (KT) * 32 + quad * 8;                               \
        int koC_ = koA_ > (VDIM - 8) ? (VDIM - 8) : koA_;              \
        ar0 = *reinterpret_cast<const f32x4*>(ap0 + koC_);             \
        ar1 = *reinterpret_cast<const f32x4*>(ap0 + koC_ + 4);         \
        ar2 = *reinterpret_cast<const f32x4*>(ap1 + koC_);             \
        ar3 = *reinterpret_cast<const f32x4*>(ap1 + koC_ + 4);         \
    } while (0)

#define CONVA(KT) do {                                                 \
        int ko_ = (KT) * 32 + quad * 8;                                \
        if (ko_ < VDIM) {                                              \
            af0[0]=(short)f2bf(ar0[0]); af0[1]=(short)f2bf(ar0[1]);    \
            af0[2]=(short)f2bf(ar0[2]); af0[3]=(short)f2bf(ar0[3]);    \
            af0[4]=(short)f2bf(ar1[0]); af0[5]=(short)f2bf(ar1[1]);    \
            af0[6]=(short)f2bf(ar1[2]); af0[7]=(short)f2bf(ar1[3]);    \
            af1[0]=(short)f2bf(ar2[0]); af1[1]=(short)f2bf(ar2[1]);    \
            af1[2]=(short)f2bf(ar2[2]); af1[3]=(short)f2bf(ar2[3]);    \
            af1[4]=(short)f2bf(ar3[0]); af1[5]=(short)f2bf(ar3[1]);    \
            af1[6]=(short)f2bf(ar3[2]); af1[7]=(short)f2bf(ar3[3]);    \
        } else {                                                       \
            af0 = (bf16x8){0,0,0,0,0,0,0,0};                           \
            af1 = (bf16x8){0,0,0,0,0,0,0,0};                           \
        }                                                              \
    } while (0)

#define DSWRITE(BUF, sa, sb) do {                                      \
        *reinterpret_cast<bf16x8*>(&bLds[BUF][scol][shalf * 16])     = sa; \
        *reinterpret_cast<bf16x8*>(&bLds[BUF][scol][shalf * 16 + 8]) = sb; \
    } while (0)

#define BODY(T, P, Sa, Sb) do {                                        \
        CONVA(T);                      /* uses A(T), waited by compiler */ \
        GLOADA((T) + 1);               /* issue A(T+1), in flight over barrier */ \
        DSWRITE((P) ^ 1, Sa, Sb);      /* publish B(T+1) for next iter */  \
        GLOADB(Sa, Sb, CLAMPK((T) + 3)); /* reissue freed pair: B(T+3) */  \
        bf16x8 b0_ = *reinterpret_cast<const bf16x8*>(&bLds[P][ 0 + l15][quad * 8]); \
        bf16x8 b1_ = *reinterpret_cast<const bf16x8*>(&bLds[P][16 + l15][quad * 8]); \
        bf16x8 b2_ = *reinterpret_cast<const bf16x8*>(&bLds[P][32 + l15][quad * 8]); \
        bf16x8 b3_ = *reinterpret_cast<const bf16x8*>(&bLds[P][48 + l15][quad * 8]); \
        acc[0][0] = __builtin_amdgcn_mfma_f32_16x16x32_bf16(af0, b0_, acc[0][0], 0, 0, 0); \
        acc[1][0] = __builtin_amdgcn_mfma_f32_16x16x32_bf16(af1, b0_, acc[1][0], 0, 0, 0); \
        acc[0][1] = __builtin_amdgcn_mfma_f32_16x16x32_bf16(af0, b1_, acc[0][1], 0, 0, 0); \
        acc[1][1] = __builtin_amdgcn_mfma_f32_16x16x32_bf16(af1, b1_, acc[1][1], 0, 0, 0); \
        acc[0][2] = __builtin_amdgcn_mfma_f32_16x16x32_bf16(af0, b2_, acc[0][2], 0, 0, 0); \
        acc[1][2] = __builtin_amdgcn_mfma_f32_16x16x32_bf16(af1, b2_, acc[1][2], 0, 0, 0); \
        acc[0][3] = __builtin_amdgcn_mfma_f32_16x16x32_bf16(af0, b3_, acc[0][3], 0, 0, 0); \
        acc[1][3] = __builtin_amdgcn_mfma_f32_16x16x32_bf16(af1, b3_, acc[1][3], 0, 0, 0); \
        bf16x8 b4_ = *reinterpret_cast<const bf16x8*>(&bLds[P][ 64 + l15][quad * 8]); \
        bf16x8 b5_ = *reinterpret_cast<const bf16x8*>(&bLds[P][ 80 + l15][quad * 8]); \
        bf16x8 b6_ = *reinterpret_cast<const bf16x8*>(&bLds[P][ 96 + l15][quad * 8]); \
        bf16x8 b7_ = *reinterpret_cast<const bf16x8*>(&bLds[P][112 + l15][quad * 8]); \
        acc[0][4] = __builtin_amdgcn_mfma_f32_16x16x32_bf16(af0, b4_, acc[0][4], 0, 0, 0); \
        acc[1][4] = __builtin_amdgcn_mfma_f32_16x16x32_bf16(af1, b4_, acc[1][4], 0, 0, 0); \
        acc[0][5] = __builtin_amdgcn_mfma_f32_16x16x32_bf16(af0, b5_, acc[0][5], 0, 0, 0); \
        acc[1][5] = __builtin_amdgcn_mfma_f32_16x16x32_bf16(af1, b5_, acc[1][5], 0, 0, 0); \
        acc[0][6] = __builtin_amdgcn_mfma_f32_16x16x32_bf16(af0, b6_, acc[0][6], 0, 0, 0); \
        acc[1][6] = __builtin_amdgcn_mfma_f32_16x16x32_bf16(af1, b6_, acc[1][6], 0, 0, 0); \
        acc[0][7] = __builtin_amdgcn_mfma_f32_16x16x32_bf16(af0, b7_, acc[0][7], 0, 0, 0); \
        acc[1][7] = __builtin_amdgcn_mfma_f32_16x16x32_bf16(af1, b7_, acc[1][7], 0, 0, 0); \
        asm volatile("s_barrier" ::: "memory");                        \
    } while (0)

    // ---- prologue: buf0 <- B(kt0); prefetch B(kt0+1), B(kt0+2), A(kt0)
    {
        bf16x8 p0_, p1_;
        GLOADB(p0_, p1_, kt0);
        DSWRITE(0, p0_, p1_);          // compiler inserts vmcnt wait for p0_/p1_
        GLOADB(sA0, sA1, CLAMPK(kt0 + 1));
        GLOADB(sB0, sB1, CLAMPK(kt0 + 2));
        GLOADA(kt0);
        asm volatile("s_waitcnt lgkmcnt(0)" ::: "memory");  // ds_write drained
        asm volatile("s_barrier" ::: "memory");             // publish buf0
    }

    int kt = kt0;
    while (true) {
        BODY(kt, 0, sA0, sA1);
        if (++kt >= kt1) break;
        BODY(kt, 1, sB0, sB1);
        if (++kt >= kt1) break;
    }

    // epilogue: C/D layout col = lane&15, row = quad*4 + reg
    float* rp = reps + (size_t)s * NROW * DDIM + (size_t)r0 * DDIM;
    #pragma unroll
    for (int rf = 0; rf < 2; ++rf)
        #pragma unroll
        for (int ct = 0; ct < 8; ++ct)
            #pragma unroll
            for (int r = 0; r < 4; ++r)
                atomicAdd(rp + (size_t)(rf * 16 + quad * 4 + r) * DDIM + ct * 16 + l15,
                          acc[rf][ct][r]);
#undef BODY
#undef DSWRITE
#undef CONVA
#undef GLOADA
#undef GLOADB
#undef CLAMPK
}

// ---------------------------------------------------------------------------
// Kernel 3: f_pos/f_neg row dots + hinge loss. wave-per-row, block = 4 waves
// ---------------------------------------------------------------------------
__global__ __launch_bounds__(256) void finalize(
    const float* __restrict__ reps, float* __restrict__ out)
{
    __shared__ float ls[4];
    const int wid  = threadIdx.x >> 6;
    const int lane = threadIdx.x & 63;
    const int row  = blockIdx.x * 4 + wid;

    const float* c = reps + (size_t)row * DDIM + 2 * lane;
    const float* r = c + (size_t)NROW * DDIM;
    const float* n = r + (size_t)NROW * DDIM;
    const float2 cv = *reinterpret_cast<const float2*>(c);
    const float2 rv = *reinterpret_cast<const float2*>(r);
    const float2 nv = *reinterpret_cast<const float2*>(n);

    float fp = cv.x * rv.x + cv.y * rv.y;
    float fn = cv.x * nv.x + cv.y * nv.y;
    #pragma unroll
    for (int off = 32; off > 0; off >>= 1) {
        fp += __shfl_down(fp, off);
        fn += __shfl_down(fn, off);
    }
    if (lane == 0) {
        out[row]        = fp;
        out[NROW + row] = fn;
        float t = fn - fp + 0.5f;
        ls[wid] = t > 0.f ? t : 0.f;
    }
    __syncthreads();
    if (threadIdx.x == 0)
        atomicAdd(out + 2 * NROW, ls[0] + ls[1] + ls[2] + ls[3]);
}

// ---------------------------------------------------------------------------
extern "C" void kernel_launch(void* const* d_in, const int* in_sizes, int n_in,
                              void* d_out, int out_size, void* d_ws, size_t ws_size,
                              hipStream_t stream)
{
    const float* cb  = (const float*)d_in[0];
    const float* rbb = (const float*)d_in[1];
    const float* nb  = (const float*)d_in[2];
    const float* ce  = (const float*)d_in[3];
    const float* re  = (const float*)d_in[4];
    float* out = (float*)d_out;

    unsigned short* emb = (unsigned short*)d_ws;
    const size_t embBytes = (size_t)2 * DDIM * VPAD * sizeof(unsigned short);
    float* reps = (float*)((char*)d_ws + embBytes);
    const size_t repBytes = (size_t)3 * NROW * DDIM * sizeof(float);

    convert_emb<<<dim3((2 * DDIM * VPAD / 8) / 256), dim3(256), 0, stream>>>(ce, re, emb);
    hipMemsetAsync(reps, 0, repBytes, stream);
    hipMemsetAsync(out + 2 * NROW, 0, sizeof(float), stream);
    gemm_rep<<<dim3(NROW / 128, 3, KSPLIT), dim3(256), 0, stream>>>(cb, rbb, nb, emb, reps);
    finalize<<<dim3(NROW / 4), dim3(256), 0, stream>>>(reps, out);
}

// Round 5
// 202.139 us; speedup vs baseline: 1.0255x; 1.0255x over previous
//
#include <hip/hip_runtime.h>
#include <hip/hip_bf16.h>
#include <cstdint>

#define VDIM 10000
#define VPAD 10016          // 313 * 32, zero-padded K for MFMA
#define NROW 4096
#define DDIM 128
#define KSTEPS 313          // ceil(10000/32)
#define KSPLIT 8
#define KCHUNK 40           // ceil(313/8)
#define RBLK 64             // rows per block (4 waves x 16 rows)

typedef __attribute__((ext_vector_type(8))) short bf16x8;
typedef __attribute__((ext_vector_type(4))) float f32x4;

__device__ __forceinline__ unsigned short f2bf(float f) {
    union { float f; unsigned u; } v; v.f = f;
    unsigned u = v.u;
    unsigned r = (u + 0x7FFFu + ((u >> 16) & 1u)) >> 16;  // RNE
    return (unsigned short)r;
}

// ---------------------------------------------------------------------------
// Kernel 1: convert embeddings fp32 [128][10000] -> bf16 [2][128][10016], pad=0
// ---------------------------------------------------------------------------
__global__ __launch_bounds__(256) void convert_emb(
    const float* __restrict__ ec, const float* __restrict__ er,
    unsigned short* __restrict__ out)
{
    int idx8 = (blockIdx.x * 256 + threadIdx.x) * 8;
    const int total = 2 * DDIM * VPAD;
    if (idx8 >= total) return;
    int e   = idx8 / (DDIM * VPAD);
    int rem = idx8 - e * (DDIM * VPAD);
    int row = rem / VPAD;
    int k   = rem - row * VPAD;
    unsigned short o[8];
    if (k < VDIM) {
        const float* src = (e ? er : ec) + row * VDIM + k;
        #pragma unroll
        for (int j = 0; j < 8; ++j) o[j] = f2bf(src[j]);
    } else {
        #pragma unroll
        for (int j = 0; j < 8; ++j) o[j] = 0;
    }
    *reinterpret_cast<bf16x8*>(out + idx8) = *reinterpret_cast<const bf16x8*>(o);
}

// ---------------------------------------------------------------------------
// Kernel 2: three GEMMs [4096,10000]x[10000,128] -> reps[3][4096][128] (f32)
// grid = (64 rb x 3 stream x 8 kc) = 1536 blocks -> 6 blocks/CU, 24 waves/CU.
// block = 256 (4 waves); wave owns 16 rows x 128 cols (acc = 32 VGPR).
// B K-tile (32k x 128col) LDS-staged per block per kt, double-buffered via
// reg prefetch depth 1; A reg-prefetched depth 1; one __syncthreads per kt.
// TLP (6 blocks/CU) is the latency-hiding mechanism (m114).
// ---------------------------------------------------------------------------
__global__ __launch_bounds__(256, 6) void gemm_rep(
    const float* __restrict__ a0, const float* __restrict__ a1,
    const float* __restrict__ a2,
    const unsigned short* __restrict__ emb,   // [2][128][VPAD] bf16
    float* __restrict__ reps)                 // [3][4096][128] f32 (zeroed)
{
    __shared__ short bLds[2][DDIM][40];       // 20,480 B, padded rows (80 B)

    const int rb = blockIdx.x;
    const int s  = blockIdx.y;
    const int kc = blockIdx.z;
    const float* A = (s == 0) ? a0 : (s == 1 ? a1 : a2);
    const unsigned short* E = emb + (size_t)(s == 0 ? 0 : 1) * (DDIM * VPAD);

    const int tid  = threadIdx.x;
    const int wave = tid >> 6;
    const int lane = tid & 63;
    const int l15  = lane & 15;
    const int quad = lane >> 4;

    // B staging: thread t owns col=t>>1, half=t&1 (16 shorts = 32 B)
    const int scol  = tid >> 1;
    const int shalf = tid & 1;
    const unsigned short* sp = E + (size_t)scol * VPAD + shalf * 16;

    const int kt0 = kc * KCHUNK;
    const int kt1 = (kt0 + KCHUNK < KSTEPS) ? (kt0 + KCHUNK) : KSTEPS;

    const int r0 = rb * RBLK + wave * 16;
    const float* ap = A + (size_t)(r0 + l15) * VDIM;   // one row per lane-group

    f32x4 acc[8];
    #pragma unroll
    for (int ct = 0; ct < 8; ++ct) acc[ct] = (f32x4){0.f, 0.f, 0.f, 0.f};

    bf16x8 sB0, sB1;     // B stage pair (reused each kt; WAR ordered by ds_write)
    f32x4 ar0, ar1;      // raw A for kt (8 floats, one row-fragment)
    bf16x8 af;           // converted A fragment

#define GLOADB(sa, sb, KT) do {                                        \
        const unsigned short* q_ = sp + (size_t)(KT) * 32;             \
        sa = *reinterpret_cast<const bf16x8*>(q_);                     \
        sb = *reinterpret_cast<const bf16x8*>(q_ + 8);                 \
    } while (0)

#define GLOADA(KT) do {                                                \
        int koA_ = (KT) * 32 + quad * 8;                               \
        int koC_ = koA_ > (VDIM - 8) ? (VDIM - 8) : koA_;              \
        ar0 = *reinterpret_cast<const f32x4*>(ap + koC_);              \
        ar1 = *reinterpret_cast<const f32x4*>(ap + koC_ + 4);          \
    } while (0)

#define CONVA(KT) do {                                                 \
        int ko_ = (KT) * 32 + quad * 8;                                \
        if (ko_ < VDIM) {                                              \
            af[0]=(short)f2bf(ar0[0]); af[1]=(short)f2bf(ar0[1]);      \
            af[2]=(short)f2bf(ar0[2]); af[3]=(short)f2bf(ar0[3]);      \
            af[4]=(short)f2bf(ar1[0]); af[5]=(short)f2bf(ar1[1]);      \
            af[6]=(short)f2bf(ar1[2]); af[7]=(short)f2bf(ar1[3]);      \
        } else {                                                       \
            af = (bf16x8){0,0,0,0,0,0,0,0};                            \
        }                                                              \
    } while (0)

#define DSWRITE(BUF, sa, sb) do {                                      \
        *reinterpret_cast<bf16x8*>(&bLds[BUF][scol][shalf * 16])     = sa; \
        *reinterpret_cast<bf16x8*>(&bLds[BUF][scol][shalf * 16 + 8]) = sb; \
    } while (0)

#define BODY(T, P) do {                                                \
        CONVA(T);                        /* A(T) arrived (issued T-1) */ \
        if ((T) + 1 < kt1) {                                           \
            GLOADA((T) + 1);             /* prefetch A(T+1) */          \
            DSWRITE((P) ^ 1, sB0, sB1);  /* publish B(T+1) */           \
        }                                                              \
        if ((T) + 2 < kt1) GLOADB(sB0, sB1, (T) + 2);                  \
        bf16x8 b0_ = *reinterpret_cast<const bf16x8*>(&bLds[P][ 0 + l15][quad * 8]); \
        bf16x8 b1_ = *reinterpret_cast<const bf16x8*>(&bLds[P][16 + l15][quad * 8]); \
        bf16x8 b2_ = *reinterpret_cast<const bf16x8*>(&bLds[P][32 + l15][quad * 8]); \
        bf16x8 b3_ = *reinterpret_cast<const bf16x8*>(&bLds[P][48 + l15][quad * 8]); \
        acc[0] = __builtin_amdgcn_mfma_f32_16x16x32_bf16(af, b0_, acc[0], 0, 0, 0); \
        acc[1] = __builtin_amdgcn_mfma_f32_16x16x32_bf16(af, b1_, acc[1], 0, 0, 0); \
        acc[2] = __builtin_amdgcn_mfma_f32_16x16x32_bf16(af, b2_, acc[2], 0, 0, 0); \
        acc[3] = __builtin_amdgcn_mfma_f32_16x16x32_bf16(af, b3_, acc[3], 0, 0, 0); \
        bf16x8 b4_ = *reinterpret_cast<const bf16x8*>(&bLds[P][ 64 + l15][quad * 8]); \
        bf16x8 b5_ = *reinterpret_cast<const bf16x8*>(&bLds[P][ 80 + l15][quad * 8]); \
        bf16x8 b6_ = *reinterpret_cast<const bf16x8*>(&bLds[P][ 96 + l15][quad * 8]); \
        bf16x8 b7_ = *reinterpret_cast<const bf16x8*>(&bLds[P][112 + l15][quad * 8]); \
        acc[4] = __builtin_amdgcn_mfma_f32_16x16x32_bf16(af, b4_, acc[4], 0, 0, 0); \
        acc[5] = __builtin_amdgcn_mfma_f32_16x16x32_bf16(af, b5_, acc[5], 0, 0, 0); \
        acc[6] = __builtin_amdgcn_mfma_f32_16x16x32_bf16(af, b6_, acc[6], 0, 0, 0); \
        acc[7] = __builtin_amdgcn_mfma_f32_16x16x32_bf16(af, b7_, acc[7], 0, 0, 0); \
    } while (0)

    // ---- prologue: buf0 <- B(kt0); prefetch B(kt0+1) regs, A(kt0) regs
    {
        bf16x8 p0_, p1_;
        GLOADB(p0_, p1_, kt0);
        DSWRITE(0, p0_, p1_);            // compiler waits vmcnt before ds_write
        GLOADB(sB0, sB1, kt0 + 1);       // KCHUNK >= 2 always
        GLOADA(kt0);
        __syncthreads();
    }

    int kt = kt0;
    while (true) {
        BODY(kt, 0);
        if (++kt >= kt1) break;
        __syncthreads();
        BODY(kt, 1);
        if (++kt >= kt1) break;
        __syncthreads();
    }

    // epilogue: C/D layout col = lane&15, row = quad*4 + reg
    float* rp = reps + (size_t)s * NROW * DDIM + (size_t)r0 * DDIM;
    #pragma unroll
    for (int ct = 0; ct < 8; ++ct)
        #pragma unroll
        for (int r = 0; r < 4; ++r)
            atomicAdd(rp + (size_t)(quad * 4 + r) * DDIM + ct * 16 + l15,
                      acc[ct][r]);
#undef BODY
#undef DSWRITE
#undef CONVA
#undef GLOADA
#undef GLOADB
}

// ---------------------------------------------------------------------------
// Kernel 3: f_pos/f_neg row dots + hinge loss. wave-per-row, block = 4 waves
// ---------------------------------------------------------------------------
__global__ __launch_bounds__(256) void finalize(
    const float* __restrict__ reps, float* __restrict__ out)
{
    __shared__ float ls[4];
    const int wid  = threadIdx.x >> 6;
    const int lane = threadIdx.x & 63;
    const int row  = blockIdx.x * 4 + wid;

    const float* c = reps + (size_t)row * DDIM + 2 * lane;
    const float* r = c + (size_t)NROW * DDIM;
    const float* n = r + (size_t)NROW * DDIM;
    const float2 cv = *reinterpret_cast<const float2*>(c);
    const float2 rv = *reinterpret_cast<const float2*>(r);
    const float2 nv = *reinterpret_cast<const float2*>(n);

    float fp = cv.x * rv.x + cv.y * rv.y;
    float fn = cv.x * nv.x + cv.y * nv.y;
    #pragma unroll
    for (int off = 32; off > 0; off >>= 1) {
        fp += __shfl_down(fp, off);
        fn += __shfl_down(fn, off);
    }
    if (lane == 0) {
        out[row]        = fp;
        out[NROW + row] = fn;
        float t = fn - fp + 0.5f;
        ls[wid] = t > 0.f ? t : 0.f;
    }
    __syncthreads();
    if (threadIdx.x == 0)
        atomicAdd(out + 2 * NROW, ls[0] + ls[1] + ls[2] + ls[3]);
}

// ---------------------------------------------------------------------------
extern "C" void kernel_launch(void* const* d_in, const int* in_sizes, int n_in,
                              void* d_out, int out_size, void* d_ws, size_t ws_size,
                              hipStream_t stream)
{
    const float* cb  = (const float*)d_in[0];
    const float* rbb = (const float*)d_in[1];
    const float* nb  = (const float*)d_in[2];
    const float* ce  = (const float*)d_in[3];
    const float* re  = (const float*)d_in[4];
    float* out = (float*)d_out;

    unsigned short* emb = (unsigned short*)d_ws;
    const size_t embBytes = (size_t)2 * DDIM * VPAD * sizeof(unsigned short);
    float* reps = (float*)((char*)d_ws + embBytes);
    const size_t repBytes = (size_t)3 * NROW * DDIM * sizeof(float);

    convert_emb<<<dim3((2 * DDIM * VPAD / 8) / 256), dim3(256), 0, stream>>>(ce, re, emb);
    hipMemsetAsync(reps, 0, repBytes, stream);
    hipMemsetAsync(out + 2 * NROW, 0, sizeof(float), stream);
    gemm_rep<<<dim3(NROW / RBLK, 3, KSPLIT), dim3(256), 0, stream>>>(cb, rbb, nb, emb, reps);
    finalize<<<dim3(NROW / 4), dim3(256), 0, stream>>>(reps, out);
}